// Round 1
// 1386.507 us; speedup vs baseline: 1.0798x; 1.0798x over previous
//
#include <hip/hip_runtime.h>
#include <stdint.h>

#define B_  2
#define H_  8
#define S_  4096
#define DM_ 512
#define DK_ 64
#define BH_ (B_*H_)

using f32x4 = __attribute__((ext_vector_type(4))) float;
using s16x8 = __attribute__((ext_vector_type(8))) short;
using u16x4 = __attribute__((ext_vector_type(4))) unsigned short;
using u16x8 = __attribute__((ext_vector_type(8))) unsigned short;

__device__ __forceinline__ unsigned short f2bf(float f) {
    unsigned int u = __float_as_uint(f);
    u += 0x7FFFu + ((u >> 16) & 1u);          // RNE
    return (unsigned short)(u >> 16);
}
__device__ __forceinline__ float bf2f(unsigned short h) {
    return __uint_as_float(((unsigned int)h) << 16);
}

// ---------------------------------------------------------------------------
// Pre-pass: fp32 -> bf16 hi + bf16 residual lo (vectorized, grid-stride).
// Hoists the split conversion out of the GEMM k-loops (was redundant 8x/128x).
// ---------------------------------------------------------------------------
__global__ __launch_bounds__(256) void convert_split(const float* __restrict__ in,
        unsigned short* __restrict__ hi, unsigned short* __restrict__ lo, int n4)
{
    for (int i = blockIdx.x*256 + threadIdx.x; i < n4; i += gridDim.x*256) {
        float4 v = ((const float4*)in)[i];
        float s4[4] = {v.x, v.y, v.z, v.w};
        u16x4 h, l;
#pragma unroll
        for (int j = 0; j < 4; ++j) {
            unsigned short hh = f2bf(s4[j]);
            h[j] = hh; l[j] = f2bf(s4[j] - bf2f(hh));
        }
        ((u16x4*)hi)[i] = h;
        ((u16x4*)lo)[i] = l;
    }
}

__global__ __launch_bounds__(256) void convert_hi(const float* __restrict__ in,
        unsigned short* __restrict__ hi, int n4)
{
    for (int i = blockIdx.x*256 + threadIdx.x; i < n4; i += gridDim.x*256) {
        float4 v = ((const float4*)in)[i];
        u16x4 h;
        h[0] = f2bf(v.x); h[1] = f2bf(v.y); h[2] = f2bf(v.z); h[3] = f2bf(v.w);
        ((u16x4*)hi)[i] = h;
    }
}

// ---------------------------------------------------------------------------
// Projection GEMM: Y[m][n] = (sum_k X[m][k]*W[n][k] + bias[n]) * scale
// Pure-bf16 inputs (preconverted hi/lo), BK=64, 24 MFMAs per barrier pair.
// MFMA order per 32-k chunk kept as (hh, hl, lh) -> bit-identical to previous.
// MODE 0: Y stored [b][h][s][d]   (q, k)
// MODE 1: Y stored [b][h][d][s]   (v transposed, for PV B-operand)
// ---------------------------------------------------------------------------
template<int MODE>
__global__ __launch_bounds__(256) void proj_kernel(
        const unsigned short* __restrict__ Xh, const unsigned short* __restrict__ Xl,
        const unsigned short* __restrict__ Wh, const unsigned short* __restrict__ Wl,
        const float* __restrict__ bias, unsigned short* __restrict__ Y, float scale)
{
    __shared__ __align__(16) unsigned short xh[64*72], xl[64*72];
    __shared__ __align__(16) unsigned short wh[64*72], wl[64*72];
    const int tid  = threadIdx.x;
    const int wave = tid >> 6, lane = tid & 63, lq = lane >> 4, lr = lane & 15;
    const int m0 = blockIdx.x * 64, n0 = blockIdx.y * 64;

    f32x4 acc[4] = {{0.f,0.f,0.f,0.f},{0.f,0.f,0.f,0.f},
                    {0.f,0.f,0.f,0.f},{0.f,0.f,0.f,0.f}};

    for (int kk = 0; kk < 8; ++kk) {
        __syncthreads();
#pragma unroll
        for (int p = 0; p < 2; ++p) {
            int idx = tid + p*256;
            int row = idx >> 3, seg = idx & 7;
            size_t xoff = (size_t)(m0+row)*DM_ + kk*64 + seg*8;
            size_t woff = (size_t)(n0+row)*DM_ + kk*64 + seg*8;
            *(u16x8*)&xh[row*72 + seg*8] = *(const u16x8*)&Xh[xoff];
            *(u16x8*)&xl[row*72 + seg*8] = *(const u16x8*)&Xl[xoff];
            *(u16x8*)&wh[row*72 + seg*8] = *(const u16x8*)&Wh[woff];
            *(u16x8*)&wl[row*72 + seg*8] = *(const u16x8*)&Wl[woff];
        }
        __syncthreads();
        const int ar = wave*16 + lr;
        s16x8 ah0 = *(const s16x8*)&xh[ar*72 +  0 + lq*8];
        s16x8 ah1 = *(const s16x8*)&xh[ar*72 + 32 + lq*8];
        s16x8 al0 = *(const s16x8*)&xl[ar*72 +  0 + lq*8];
        s16x8 al1 = *(const s16x8*)&xl[ar*72 + 32 + lq*8];
#pragma unroll
        for (int nt = 0; nt < 4; ++nt) {
            int br = nt*16 + lr;
            s16x8 bh0 = *(const s16x8*)&wh[br*72 +  0 + lq*8];
            s16x8 bh1 = *(const s16x8*)&wh[br*72 + 32 + lq*8];
            s16x8 bl0 = *(const s16x8*)&wl[br*72 +  0 + lq*8];
            s16x8 bl1 = *(const s16x8*)&wl[br*72 + 32 + lq*8];
            acc[nt] = __builtin_amdgcn_mfma_f32_16x16x32_bf16(ah0, bh0, acc[nt], 0, 0, 0);
            acc[nt] = __builtin_amdgcn_mfma_f32_16x16x32_bf16(ah0, bl0, acc[nt], 0, 0, 0);
            acc[nt] = __builtin_amdgcn_mfma_f32_16x16x32_bf16(al0, bh0, acc[nt], 0, 0, 0);
            acc[nt] = __builtin_amdgcn_mfma_f32_16x16x32_bf16(ah1, bh1, acc[nt], 0, 0, 0);
            acc[nt] = __builtin_amdgcn_mfma_f32_16x16x32_bf16(ah1, bl1, acc[nt], 0, 0, 0);
            acc[nt] = __builtin_amdgcn_mfma_f32_16x16x32_bf16(al1, bh1, acc[nt], 0, 0, 0);
        }
    }
#pragma unroll
    for (int nt = 0; nt < 4; ++nt)
#pragma unroll
        for (int r = 0; r < 4; ++r) {
            int m = m0 + wave*16 + lq*4 + r;
            int n = n0 + nt*16 + lr;
            float v = (acc[nt][r] + bias[n]) * scale;
            int b = m >> 12, s = m & 4095;
            int h = n >> 6,  d = n & 63;
            size_t addr;
            if (MODE == 0) addr = ((size_t)((b*H_ + h)*S_ + s))*DK_ + d;
            else           addr = ((size_t)((b*H_ + h)*DK_ + d))*S_ + s;
            Y[addr] = f2bf(v);
        }
}

// ---------------------------------------------------------------------------
// Stats pass: l[bh][sq] = sum_{j<=sq} exp(s(sq,j) - 16). 64-wide j-tiles,
// 2 barriers per tile. Same MFMA fragments/order as pass 2 -> l is exactly
// the sum of the p values pass 2 writes.
// ---------------------------------------------------------------------------
__global__ __launch_bounds__(256) void stats_kernel(
        const unsigned short* __restrict__ qb, const unsigned short* __restrict__ kb,
        float* __restrict__ lsum)
{
    __shared__ __align__(16) unsigned short qs[64*72], ks[64*72];
    const int tid  = threadIdx.x;
    const int wave = tid >> 6, lane = tid & 63, lq = lane >> 4, lr = lane & 15;
    const int bh = blockIdx.y;
    const int s0 = blockIdx.x * 64;

#pragma unroll
    for (int p = 0; p < 2; ++p) {
        int idx = tid + p*256;
        int row = idx >> 3, seg = idx & 7;
        *(s16x8*)&qs[row*72 + seg*8] =
            *(const s16x8*)&qb[((size_t)bh*S_ + s0 + row)*DK_ + seg*8];
    }
    __syncthreads();
    const int ar = wave*16 + lr;
    s16x8 aq0 = *(const s16x8*)&qs[ar*72 +  0 + lq*8];
    s16x8 aq1 = *(const s16x8*)&qs[ar*72 + 32 + lq*8];

    float lacc[4] = {0.f, 0.f, 0.f, 0.f};
    const int jtmax = blockIdx.x;                 // 64-wide tiles: 0..bx inclusive
    for (int jt = 0; jt <= jtmax; ++jt) {
        __syncthreads();
#pragma unroll
        for (int p = 0; p < 2; ++p) {
            int idx = tid + p*256;
            int row = idx >> 3, seg = idx & 7;
            *(s16x8*)&ks[row*72 + seg*8] =
                *(const s16x8*)&kb[((size_t)bh*S_ + jt*64 + row)*DK_ + seg*8];
        }
        __syncthreads();
#pragma unroll
        for (int nt = 0; nt < 4; ++nt) {
            int br = nt*16 + lr;
            s16x8 b0 = *(const s16x8*)&ks[br*72 +  0 + lq*8];
            s16x8 b1 = *(const s16x8*)&ks[br*72 + 32 + lq*8];
            f32x4 sc = {0.f,0.f,0.f,0.f};
            sc = __builtin_amdgcn_mfma_f32_16x16x32_bf16(aq0, b0, sc, 0, 0, 0);
            sc = __builtin_amdgcn_mfma_f32_16x16x32_bf16(aq1, b1, sc, 0, 0, 0);
            int j = jt*64 + nt*16 + lr;
#pragma unroll
            for (int r = 0; r < 4; ++r) {
                int sq = s0 + wave*16 + lq*4 + r;
                lacc[r] += (j <= sq) ? __expf(sc[r] - 16.f) : 0.f;
            }
        }
    }
#pragma unroll
    for (int r = 0; r < 4; ++r) {
        float v = lacc[r];
        for (int off = 1; off < 16; off <<= 1) v += __shfl_xor(v, off, 64);
        if (lr == 0) lsum[(size_t)bh*S_ + s0 + wave*16 + lq*4 + r] = v;
    }
}

// ---------------------------------------------------------------------------
// Pass 2: recompute scores, attn = exp(s-16)/l, write attn (fp32, zeros above
// diagonal), wave-local LDS round-trip attn->A-frag (lgkmcnt wait, no block
// barrier), PV MFMA, store O as bf16 [b][s][hd]. 64-wide j-tiles, 2 barriers
// per tile (was 3 per 32-wide tile).
// ---------------------------------------------------------------------------
__global__ __launch_bounds__(256) void attn_kernel(
        const unsigned short* __restrict__ qb, const unsigned short* __restrict__ kb,
        const unsigned short* __restrict__ vtb, const float* __restrict__ lsum,
        float* __restrict__ attn, unsigned short* __restrict__ oacc)
{
    __shared__ __align__(16) unsigned short qs[64*72], ks[64*72], vs[64*72];
    __shared__ __align__(16) unsigned short ps[4][16*72];
    __shared__ float invl[64];
    const int tid  = threadIdx.x;
    const int wave = tid >> 6, lane = tid & 63, lq = lane >> 4, lr = lane & 15;
    const int bh = blockIdx.y;
    const int s0 = blockIdx.x * 64;

#pragma unroll
    for (int p = 0; p < 2; ++p) {
        int idx = tid + p*256;
        int row = idx >> 3, seg = idx & 7;
        *(s16x8*)&qs[row*72 + seg*8] =
            *(const s16x8*)&qb[((size_t)bh*S_ + s0 + row)*DK_ + seg*8];
    }
    if (tid < 64) invl[tid] = 1.0f / lsum[(size_t)bh*S_ + s0 + tid];
    __syncthreads();
    const int ar = wave*16 + lr;
    s16x8 aq0 = *(const s16x8*)&qs[ar*72 +  0 + lq*8];
    s16x8 aq1 = *(const s16x8*)&qs[ar*72 + 32 + lq*8];
    float il[4];
#pragma unroll
    for (int r = 0; r < 4; ++r) il[r] = invl[wave*16 + lq*4 + r];

    f32x4 O[4] = {{0.f,0.f,0.f,0.f},{0.f,0.f,0.f,0.f},
                  {0.f,0.f,0.f,0.f},{0.f,0.f,0.f,0.f}};
    const int jtcomp = blockIdx.x;                // 64-wide tiles: compute 0..bx

    for (int jt = 0; jt < S_/64; ++jt) {
        if (jt <= jtcomp) {
            __syncthreads();
#pragma unroll
            for (int p = 0; p < 2; ++p) {
                int idx = tid + p*256;
                int row = idx >> 3, seg = idx & 7;
                *(s16x8*)&ks[row*72 + seg*8] =
                    *(const s16x8*)&kb[((size_t)bh*S_ + jt*64 + row)*DK_ + seg*8];
                *(s16x8*)&vs[row*72 + seg*8] =
                    *(const s16x8*)&vtb[((size_t)bh*DK_ + row)*S_ + jt*64 + seg*8];
            }
            __syncthreads();
            float a_all[4][4];
#pragma unroll
            for (int nt = 0; nt < 4; ++nt) {
                int br = nt*16 + lr;
                s16x8 b0 = *(const s16x8*)&ks[br*72 +  0 + lq*8];
                s16x8 b1 = *(const s16x8*)&ks[br*72 + 32 + lq*8];
                f32x4 sc = {0.f,0.f,0.f,0.f};
                sc = __builtin_amdgcn_mfma_f32_16x16x32_bf16(aq0, b0, sc, 0, 0, 0);
                sc = __builtin_amdgcn_mfma_f32_16x16x32_bf16(aq1, b1, sc, 0, 0, 0);
                int j = jt*64 + nt*16 + lr;
#pragma unroll
                for (int r = 0; r < 4; ++r) {
                    int sq = s0 + wave*16 + lq*4 + r;
                    float p = (j <= sq) ? __expf(sc[r] - 16.f) : 0.f;
                    float a = p * il[r];
                    a_all[nt][r] = a;
                    ps[wave][(lq*4 + r)*72 + nt*16 + lr] = f2bf(a);
                }
            }
            // ps is written and read by the SAME wave: a wave-local LDS drain
            // suffices (no block barrier needed).
            asm volatile("s_waitcnt lgkmcnt(0)" ::: "memory");
            __builtin_amdgcn_sched_barrier(0);
            s16x8 ap0 = *(const s16x8*)&ps[wave][lr*72 +  0 + lq*8];
            s16x8 ap1 = *(const s16x8*)&ps[wave][lr*72 + 32 + lq*8];
#pragma unroll
            for (int nt = 0; nt < 4; ++nt) {
                s16x8 bv0 = *(const s16x8*)&vs[(nt*16 + lr)*72 +  0 + lq*8];
                s16x8 bv1 = *(const s16x8*)&vs[(nt*16 + lr)*72 + 32 + lq*8];
                O[nt] = __builtin_amdgcn_mfma_f32_16x16x32_bf16(ap0, bv0, O[nt], 0, 0, 0);
                O[nt] = __builtin_amdgcn_mfma_f32_16x16x32_bf16(ap1, bv1, O[nt], 0, 0, 0);
            }
            // attn stores issued after PV so their drain overlaps the MFMAs
            // and retires at the next tile's barrier.
#pragma unroll
            for (int nt = 0; nt < 4; ++nt)
#pragma unroll
                for (int r = 0; r < 4; ++r) {
                    int sq = s0 + wave*16 + lq*4 + r;
                    attn[((size_t)bh*S_ + sq)*S_ + jt*64 + nt*16 + lr] = a_all[nt][r];
                }
        } else {
            // fully-masked tile: fast zero fill (upper triangle must be 0.0f)
#pragma unroll
            for (int p = 0; p < 4; ++p) {
                int idx = tid + p*256;
                int row = idx >> 4, c4 = idx & 15;
                float4 z = {0.f, 0.f, 0.f, 0.f};
                *(float4*)&attn[((size_t)bh*S_ + s0 + row)*S_ + jt*64 + c4*4] = z;
            }
        }
    }
    const int b = bh >> 3, h = bh & 7;
#pragma unroll
    for (int nt = 0; nt < 4; ++nt)
#pragma unroll
        for (int r = 0; r < 4; ++r) {
            int s = s0 + wave*16 + lq*4 + r;
            oacc[((size_t)(b*S_ + s))*DM_ + h*DK_ + nt*16 + lr] = f2bf(O[nt][r]);
        }
}

// ---------------------------------------------------------------------------
// Output projection: out[m][n] = sum_k AttnOut[m][k]*Wo[n][k] + bo[n] (fp32)
// Wo preconverted to bf16 hi; BK=64.
// ---------------------------------------------------------------------------
__global__ __launch_bounds__(256) void outproj_kernel(
        const unsigned short* __restrict__ Xin, const unsigned short* __restrict__ Woh,
        const float* __restrict__ bias, float* __restrict__ out)
{
    __shared__ __align__(16) unsigned short xs[64*72], wsm[64*72];
    const int tid  = threadIdx.x;
    const int wave = tid >> 6, lane = tid & 63, lq = lane >> 4, lr = lane & 15;
    const int m0 = blockIdx.x * 64, n0 = blockIdx.y * 64;

    f32x4 acc[4] = {{0.f,0.f,0.f,0.f},{0.f,0.f,0.f,0.f},
                    {0.f,0.f,0.f,0.f},{0.f,0.f,0.f,0.f}};

    for (int kk = 0; kk < 8; ++kk) {
        __syncthreads();
#pragma unroll
        for (int p = 0; p < 2; ++p) {
            int idx = tid + p*256;
            int row = idx >> 3, seg = idx & 7;
            *(s16x8*)&xs [row*72 + seg*8] =
                *(const s16x8*)&Xin[(size_t)(m0+row)*DM_ + kk*64 + seg*8];
            *(s16x8*)&wsm[row*72 + seg*8] =
                *(const s16x8*)&Woh[(size_t)(n0+row)*DM_ + kk*64 + seg*8];
        }
        __syncthreads();
        const int ar = wave*16 + lr;
        s16x8 a0 = *(const s16x8*)&xs[ar*72 +  0 + lq*8];
        s16x8 a1 = *(const s16x8*)&xs[ar*72 + 32 + lq*8];
#pragma unroll
        for (int nt = 0; nt < 4; ++nt) {
            int br = nt*16 + lr;
            s16x8 b0 = *(const s16x8*)&wsm[br*72 +  0 + lq*8];
            s16x8 b1 = *(const s16x8*)&wsm[br*72 + 32 + lq*8];
            acc[nt] = __builtin_amdgcn_mfma_f32_16x16x32_bf16(a0, b0, acc[nt], 0, 0, 0);
            acc[nt] = __builtin_amdgcn_mfma_f32_16x16x32_bf16(a1, b1, acc[nt], 0, 0, 0);
        }
    }
#pragma unroll
    for (int nt = 0; nt < 4; ++nt)
#pragma unroll
        for (int r = 0; r < 4; ++r) {
            int m = m0 + wave*16 + lq*4 + r;
            int n = n0 + nt*16 + lr;
            out[(size_t)m*DM_ + n] = acc[nt][r] + bias[n];
        }
}

// ---------------------------------------------------------------------------
extern "C" void kernel_launch(void* const* d_in, const int* in_sizes, int n_in,
                              void* d_out, int out_size, void* d_ws, size_t ws_size,
                              hipStream_t stream)
{
    const float* Q  = (const float*)d_in[0];
    const float* K  = (const float*)d_in[1];
    const float* V  = (const float*)d_in[2];
    const float* Wq = (const float*)d_in[3];  const float* bq = (const float*)d_in[4];
    const float* Wk = (const float*)d_in[5];  const float* bk = (const float*)d_in[6];
    const float* Wv = (const float*)d_in[7];  const float* bv = (const float*)d_in[8];
    const float* Wo = (const float*)d_in[9];  const float* bo = (const float*)d_in[10];

    char* ws = (char*)d_ws;
    const size_t QKV_BYTES = (size_t)BH_ * S_ * DK_ * sizeof(unsigned short); // 8,388,608
    const size_t W_BYTES   = (size_t)DM_ * DM_ * sizeof(unsigned short);      //   524,288
    unsigned short* qbf  = (unsigned short*)(ws);
    unsigned short* kbf  = (unsigned short*)(ws + QKV_BYTES);
    unsigned short* vtb  = (unsigned short*)(ws + 2*QKV_BYTES);
    float*          lsum = (float*)(ws + 3*QKV_BYTES);                        // 262,144 B
    unsigned short* oacc = (unsigned short*)(ws + 3*QKV_BYTES + (size_t)BH_*S_*sizeof(float));
    char* p = ws + 4*QKV_BYTES + (size_t)BH_*S_*sizeof(float);
    unsigned short* xh  = (unsigned short*)(p);               p += QKV_BYTES; // 8192x512 bf16
    unsigned short* xl  = (unsigned short*)(p);               p += QKV_BYTES;
    unsigned short* wqh = (unsigned short*)(p);               p += W_BYTES;
    unsigned short* wql = (unsigned short*)(p);               p += W_BYTES;
    unsigned short* wkh = (unsigned short*)(p);               p += W_BYTES;
    unsigned short* wkl = (unsigned short*)(p);               p += W_BYTES;
    unsigned short* wvh = (unsigned short*)(p);               p += W_BYTES;
    unsigned short* wvl = (unsigned short*)(p);               p += W_BYTES;
    unsigned short* woh = (unsigned short*)(p);               p += W_BYTES;   // total ~54.3 MB

    float* out0 = (float*)d_out;
    float* attn = out0 + (size_t)B_ * S_ * DM_;

    dim3 blk(256);
    const int n4x = B_*S_*DM_/4;   // 1,048,576 float4 groups
    const int n4w = DM_*DM_/4;     //    65,536
    auto cgrid = [](int n4) { int g = (n4 + 255) / 256; return g > 2048 ? 2048 : g; };

    convert_split<<<cgrid(n4w), blk, 0, stream>>>(Wq, wqh, wql, n4w);
    convert_split<<<cgrid(n4w), blk, 0, stream>>>(Wk, wkh, wkl, n4w);
    convert_split<<<cgrid(n4w), blk, 0, stream>>>(Wv, wvh, wvl, n4w);
    convert_hi   <<<cgrid(n4w), blk, 0, stream>>>(Wo, woh, n4w);

    convert_split<<<cgrid(n4x), blk, 0, stream>>>(Q, xh, xl, n4x);
    proj_kernel<0><<<dim3(128, 8), blk, 0, stream>>>(xh, xl, wqh, wql, bq, qbf, 0.125f);
    convert_split<<<cgrid(n4x), blk, 0, stream>>>(K, xh, xl, n4x);
    proj_kernel<0><<<dim3(128, 8), blk, 0, stream>>>(xh, xl, wkh, wkl, bk, kbf, 1.0f);
    convert_split<<<cgrid(n4x), blk, 0, stream>>>(V, xh, xl, n4x);
    proj_kernel<1><<<dim3(128, 8), blk, 0, stream>>>(xh, xl, wvh, wvl, bv, vtb, 1.0f);

    stats_kernel  <<<dim3(64, 16), blk, 0, stream>>>(qbf, kbf, lsum);
    attn_kernel   <<<dim3(64, 16), blk, 0, stream>>>(qbf, kbf, vtb, lsum, attn, oacc);
    outproj_kernel<<<dim3(128, 8), blk, 0, stream>>>(oacc, woh, bo, out0);
}

// Round 3
// 1357.648 us; speedup vs baseline: 1.1027x; 1.0213x over previous
//
#include <hip/hip_runtime.h>
#include <stdint.h>

#define B_  2
#define H_  8
#define S_  4096
#define DM_ 512
#define DK_ 64
#define BH_ (B_*H_)

using f32x4 = __attribute__((ext_vector_type(4))) float;
using s16x8 = __attribute__((ext_vector_type(8))) short;
using u16x4 = __attribute__((ext_vector_type(4))) unsigned short;
using u16x8 = __attribute__((ext_vector_type(8))) unsigned short;

__device__ __forceinline__ unsigned short f2bf(float f) {
    unsigned int u = __float_as_uint(f);
    u += 0x7FFFu + ((u >> 16) & 1u);          // RNE
    return (unsigned short)(u >> 16);
}
__device__ __forceinline__ float bf2f(unsigned short h) {
    return __uint_as_float(((unsigned int)h) << 16);
}

// ---------------------------------------------------------------------------
// Pre-pass: fp32 -> bf16 hi + bf16 residual lo (vectorized, grid-stride).
// ---------------------------------------------------------------------------
__global__ __launch_bounds__(256) void convert_split(const float* __restrict__ in,
        unsigned short* __restrict__ hi, unsigned short* __restrict__ lo, int n4)
{
    for (int i = blockIdx.x*256 + threadIdx.x; i < n4; i += gridDim.x*256) {
        float4 v = ((const float4*)in)[i];
        float s4[4] = {v.x, v.y, v.z, v.w};
        u16x4 h, l;
#pragma unroll
        for (int j = 0; j < 4; ++j) {
            unsigned short hh = f2bf(s4[j]);
            h[j] = hh; l[j] = f2bf(s4[j] - bf2f(hh));
        }
        ((u16x4*)hi)[i] = h;
        ((u16x4*)lo)[i] = l;
    }
}

__global__ __launch_bounds__(256) void convert_hi(const float* __restrict__ in,
        unsigned short* __restrict__ hi, int n4)
{
    for (int i = blockIdx.x*256 + threadIdx.x; i < n4; i += gridDim.x*256) {
        float4 v = ((const float4*)in)[i];
        u16x4 h;
        h[0] = f2bf(v.x); h[1] = f2bf(v.y); h[2] = f2bf(v.z); h[3] = f2bf(v.w);
        ((u16x4*)hi)[i] = h;
    }
}

// ---------------------------------------------------------------------------
// Projection GEMM: Y[m][n] = (sum_k X[m][k]*W[n][k] + bias[n]) * scale
// Pure-bf16 inputs (preconverted hi/lo), BK=64, 24 MFMAs per barrier pair.
// MODE 0: Y stored [b][h][s][d]   (q, k)
// MODE 1: Y stored [b][h][d][s]   (v transposed) -- epilogue restages the
//         64x64 tile through LDS so global stores are contiguous u16x8 along
//         s (was: 16-lane x 2B scatter at 8KB stride).
// ---------------------------------------------------------------------------
template<int MODE>
__global__ __launch_bounds__(256) void proj_kernel(
        const unsigned short* __restrict__ Xh, const unsigned short* __restrict__ Xl,
        const unsigned short* __restrict__ Wh, const unsigned short* __restrict__ Wl,
        const float* __restrict__ bias, unsigned short* __restrict__ Y, float scale)
{
    __shared__ __align__(16) unsigned short xh[64*72], xl[64*72];
    __shared__ __align__(16) unsigned short wh[64*72], wl[64*72];
    const int tid  = threadIdx.x;
    const int wave = tid >> 6, lane = tid & 63, lq = lane >> 4, lr = lane & 15;
    const int m0 = blockIdx.x * 64, n0 = blockIdx.y * 64;

    f32x4 acc[4] = {{0.f,0.f,0.f,0.f},{0.f,0.f,0.f,0.f},
                    {0.f,0.f,0.f,0.f},{0.f,0.f,0.f,0.f}};

    for (int kk = 0; kk < 8; ++kk) {
        __syncthreads();
#pragma unroll
        for (int p = 0; p < 2; ++p) {
            int idx = tid + p*256;
            int row = idx >> 3, seg = idx & 7;
            size_t xoff = (size_t)(m0+row)*DM_ + kk*64 + seg*8;
            size_t woff = (size_t)(n0+row)*DM_ + kk*64 + seg*8;
            *(u16x8*)&xh[row*72 + seg*8] = *(const u16x8*)&Xh[xoff];
            *(u16x8*)&xl[row*72 + seg*8] = *(const u16x8*)&Xl[xoff];
            *(u16x8*)&wh[row*72 + seg*8] = *(const u16x8*)&Wh[woff];
            *(u16x8*)&wl[row*72 + seg*8] = *(const u16x8*)&Wl[woff];
        }
        __syncthreads();
        const int ar = wave*16 + lr;
        s16x8 ah0 = *(const s16x8*)&xh[ar*72 +  0 + lq*8];
        s16x8 ah1 = *(const s16x8*)&xh[ar*72 + 32 + lq*8];
        s16x8 al0 = *(const s16x8*)&xl[ar*72 +  0 + lq*8];
        s16x8 al1 = *(const s16x8*)&xl[ar*72 + 32 + lq*8];
#pragma unroll
        for (int nt = 0; nt < 4; ++nt) {
            int br = nt*16 + lr;
            s16x8 bh0 = *(const s16x8*)&wh[br*72 +  0 + lq*8];
            s16x8 bh1 = *(const s16x8*)&wh[br*72 + 32 + lq*8];
            s16x8 bl0 = *(const s16x8*)&wl[br*72 +  0 + lq*8];
            s16x8 bl1 = *(const s16x8*)&wl[br*72 + 32 + lq*8];
            acc[nt] = __builtin_amdgcn_mfma_f32_16x16x32_bf16(ah0, bh0, acc[nt], 0, 0, 0);
            acc[nt] = __builtin_amdgcn_mfma_f32_16x16x32_bf16(ah0, bl0, acc[nt], 0, 0, 0);
            acc[nt] = __builtin_amdgcn_mfma_f32_16x16x32_bf16(al0, bh0, acc[nt], 0, 0, 0);
            acc[nt] = __builtin_amdgcn_mfma_f32_16x16x32_bf16(ah1, bh1, acc[nt], 0, 0, 0);
            acc[nt] = __builtin_amdgcn_mfma_f32_16x16x32_bf16(ah1, bl1, acc[nt], 0, 0, 0);
            acc[nt] = __builtin_amdgcn_mfma_f32_16x16x32_bf16(al1, bh1, acc[nt], 0, 0, 0);
        }
    }
    if (MODE == 0) {
#pragma unroll
        for (int nt = 0; nt < 4; ++nt)
#pragma unroll
            for (int r = 0; r < 4; ++r) {
                int m = m0 + wave*16 + lq*4 + r;
                int n = n0 + nt*16 + lr;
                float v = (acc[nt][r] + bias[n]) * scale;
                int b = m >> 12, s = m & 4095;
                int h = n >> 6,  d = n & 63;
                Y[((size_t)((b*H_ + h)*S_ + s))*DK_ + d] = f2bf(v);
            }
    } else {
        // Restage 64x64 tile through LDS (reuse xh), store rows along s.
        __syncthreads();
#pragma unroll
        for (int nt = 0; nt < 4; ++nt)
#pragma unroll
            for (int r = 0; r < 4; ++r) {
                int ml = wave*16 + lq*4 + r;    // s_local
                int nl = nt*16 + lr;            // d
                float v = (acc[nt][r] + bias[n0 + nl]) * scale;
                xh[nl*72 + ml] = f2bf(v);
            }
        __syncthreads();
        const int b = m0 >> 12, sbase = m0 & 4095, h = n0 >> 6;
        const int row = tid >> 2, segb = (tid & 3) * 16;
        size_t base = ((size_t)((b*H_ + h)*DK_ + row))*S_ + sbase + segb;
        *(u16x8*)&Y[base]     = *(const u16x8*)&xh[row*72 + segb];
        *(u16x8*)&Y[base + 8] = *(const u16x8*)&xh[row*72 + segb + 8];
    }
}

// ---------------------------------------------------------------------------
// Stats pass: l[bh][sq] = sum_{j<=sq} exp(s(sq,j) - 16).
// PAIRED row-blocks: grid x=32; block bx processes s0=bx*64 AND s0=(63-bx)*64
// -> every block does exactly 65 compute tiles (uniform). Fixes the XCD
// round-robin same-bx stacking imbalance (worst-CU was ~2x mean).
// ---------------------------------------------------------------------------
__global__ __launch_bounds__(256) void stats_kernel(
        const unsigned short* __restrict__ qb, const unsigned short* __restrict__ kb,
        float* __restrict__ lsum)
{
    __shared__ __align__(16) unsigned short qs[64*72], ks[64*72];
    const int tid  = threadIdx.x;
    const int wave = tid >> 6, lane = tid & 63, lq = lane >> 4, lr = lane & 15;
    const int bh = blockIdx.y;

#pragma unroll 1
    for (int half = 0; half < 2; ++half) {
        const int bx = half ? (63 - blockIdx.x) : blockIdx.x;
        const int s0 = bx * 64;
        __syncthreads();
#pragma unroll
        for (int p = 0; p < 2; ++p) {
            int idx = tid + p*256;
            int row = idx >> 3, seg = idx & 7;
            *(s16x8*)&qs[row*72 + seg*8] =
                *(const s16x8*)&qb[((size_t)bh*S_ + s0 + row)*DK_ + seg*8];
        }
        __syncthreads();
        const int ar = wave*16 + lr;
        s16x8 aq0 = *(const s16x8*)&qs[ar*72 +  0 + lq*8];
        s16x8 aq1 = *(const s16x8*)&qs[ar*72 + 32 + lq*8];

        float lacc[4] = {0.f, 0.f, 0.f, 0.f};
        for (int jt = 0; jt <= bx; ++jt) {
            __syncthreads();
#pragma unroll
            for (int p = 0; p < 2; ++p) {
                int idx = tid + p*256;
                int row = idx >> 3, seg = idx & 7;
                *(s16x8*)&ks[row*72 + seg*8] =
                    *(const s16x8*)&kb[((size_t)bh*S_ + jt*64 + row)*DK_ + seg*8];
            }
            __syncthreads();
#pragma unroll
            for (int nt = 0; nt < 4; ++nt) {
                int br = nt*16 + lr;
                s16x8 b0 = *(const s16x8*)&ks[br*72 +  0 + lq*8];
                s16x8 b1 = *(const s16x8*)&ks[br*72 + 32 + lq*8];
                f32x4 sc = {0.f,0.f,0.f,0.f};
                sc = __builtin_amdgcn_mfma_f32_16x16x32_bf16(aq0, b0, sc, 0, 0, 0);
                sc = __builtin_amdgcn_mfma_f32_16x16x32_bf16(aq1, b1, sc, 0, 0, 0);
                int j = jt*64 + nt*16 + lr;
#pragma unroll
                for (int r = 0; r < 4; ++r) {
                    int sq = s0 + wave*16 + lq*4 + r;
                    lacc[r] += (j <= sq) ? __expf(sc[r] - 16.f) : 0.f;
                }
            }
        }
#pragma unroll
        for (int r = 0; r < 4; ++r) {
            float v = lacc[r];
            for (int off = 1; off < 16; off <<= 1) v += __shfl_xor(v, off, 64);
            if (lr == 0) lsum[(size_t)bh*S_ + s0 + wave*16 + lq*4 + r] = v;
        }
    }
}

// ---------------------------------------------------------------------------
// Pass 2: recompute scores, attn = exp(s-16)/l, write attn (fp32, zeros above
// diagonal, nontemporal), wave-local LDS round-trip attn->A-frag, PV MFMA,
// store O as bf16 [b][s][hd]. PAIRED row-blocks (see stats_kernel): uniform
// 65 compute + 63 fill tiles per block.
// ---------------------------------------------------------------------------
__global__ __launch_bounds__(256) void attn_kernel(
        const unsigned short* __restrict__ qb, const unsigned short* __restrict__ kb,
        const unsigned short* __restrict__ vtb, const float* __restrict__ lsum,
        float* __restrict__ attn, unsigned short* __restrict__ oacc)
{
    __shared__ __align__(16) unsigned short qs[64*72], ks[64*72], vs[64*72];
    __shared__ __align__(16) unsigned short ps[4][16*72];
    __shared__ float invl[64];
    const int tid  = threadIdx.x;
    const int wave = tid >> 6, lane = tid & 63, lq = lane >> 4, lr = lane & 15;
    const int bh = blockIdx.y;

#pragma unroll 1
    for (int half = 0; half < 2; ++half) {
        const int bx = half ? (63 - blockIdx.x) : blockIdx.x;
        const int s0 = bx * 64;
        __syncthreads();
#pragma unroll
        for (int p = 0; p < 2; ++p) {
            int idx = tid + p*256;
            int row = idx >> 3, seg = idx & 7;
            *(s16x8*)&qs[row*72 + seg*8] =
                *(const s16x8*)&qb[((size_t)bh*S_ + s0 + row)*DK_ + seg*8];
        }
        if (tid < 64) invl[tid] = 1.0f / lsum[(size_t)bh*S_ + s0 + tid];
        __syncthreads();
        const int ar = wave*16 + lr;
        s16x8 aq0 = *(const s16x8*)&qs[ar*72 +  0 + lq*8];
        s16x8 aq1 = *(const s16x8*)&qs[ar*72 + 32 + lq*8];
        float il[4];
#pragma unroll
        for (int r = 0; r < 4; ++r) il[r] = invl[wave*16 + lq*4 + r];

        f32x4 O[4] = {{0.f,0.f,0.f,0.f},{0.f,0.f,0.f,0.f},
                      {0.f,0.f,0.f,0.f},{0.f,0.f,0.f,0.f}};

        for (int jt = 0; jt < S_/64; ++jt) {
            if (jt <= bx) {
                __syncthreads();
#pragma unroll
                for (int p = 0; p < 2; ++p) {
                    int idx = tid + p*256;
                    int row = idx >> 3, seg = idx & 7;
                    *(s16x8*)&ks[row*72 + seg*8] =
                        *(const s16x8*)&kb[((size_t)bh*S_ + jt*64 + row)*DK_ + seg*8];
                    *(s16x8*)&vs[row*72 + seg*8] =
                        *(const s16x8*)&vtb[((size_t)bh*DK_ + row)*S_ + jt*64 + seg*8];
                }
                __syncthreads();
                float a_all[4][4];
#pragma unroll
                for (int nt = 0; nt < 4; ++nt) {
                    int br = nt*16 + lr;
                    s16x8 b0 = *(const s16x8*)&ks[br*72 +  0 + lq*8];
                    s16x8 b1 = *(const s16x8*)&ks[br*72 + 32 + lq*8];
                    f32x4 sc = {0.f,0.f,0.f,0.f};
                    sc = __builtin_amdgcn_mfma_f32_16x16x32_bf16(aq0, b0, sc, 0, 0, 0);
                    sc = __builtin_amdgcn_mfma_f32_16x16x32_bf16(aq1, b1, sc, 0, 0, 0);
                    int j = jt*64 + nt*16 + lr;
#pragma unroll
                    for (int r = 0; r < 4; ++r) {
                        int sq = s0 + wave*16 + lq*4 + r;
                        float p = (j <= sq) ? __expf(sc[r] - 16.f) : 0.f;
                        float a = p * il[r];
                        a_all[nt][r] = a;
                        ps[wave][(lq*4 + r)*72 + nt*16 + lr] = f2bf(a);
                    }
                }
                // ps written and read by the SAME wave: wave-local drain only.
                asm volatile("s_waitcnt lgkmcnt(0)" ::: "memory");
                __builtin_amdgcn_sched_barrier(0);
                s16x8 ap0 = *(const s16x8*)&ps[wave][lr*72 +  0 + lq*8];
                s16x8 ap1 = *(const s16x8*)&ps[wave][lr*72 + 32 + lq*8];
#pragma unroll
                for (int nt = 0; nt < 4; ++nt) {
                    s16x8 bv0 = *(const s16x8*)&vs[(nt*16 + lr)*72 +  0 + lq*8];
                    s16x8 bv1 = *(const s16x8*)&vs[(nt*16 + lr)*72 + 32 + lq*8];
                    O[nt] = __builtin_amdgcn_mfma_f32_16x16x32_bf16(ap0, bv0, O[nt], 0, 0, 0);
                    O[nt] = __builtin_amdgcn_mfma_f32_16x16x32_bf16(ap1, bv1, O[nt], 0, 0, 0);
                }
                // attn stores after PV so their drain overlaps the MFMAs.
#pragma unroll
                for (int nt = 0; nt < 4; ++nt)
#pragma unroll
                    for (int r = 0; r < 4; ++r) {
                        int sq = s0 + wave*16 + lq*4 + r;
                        __builtin_nontemporal_store(a_all[nt][r],
                            &attn[((size_t)bh*S_ + sq)*S_ + jt*64 + nt*16 + lr]);
                    }
            } else {
                // fully-masked tile: fast zero fill (upper triangle must be 0.0f)
#pragma unroll
                for (int p = 0; p < 4; ++p) {
                    int idx = tid + p*256;
                    int row = idx >> 4, c4 = idx & 15;
                    f32x4 z = {0.f, 0.f, 0.f, 0.f};
                    __builtin_nontemporal_store(z,
                        (f32x4*)&attn[((size_t)bh*S_ + s0 + row)*S_ + jt*64 + c4*4]);
                }
            }
        }
        const int b = bh >> 3, h = bh & 7;
#pragma unroll
        for (int nt = 0; nt < 4; ++nt)
#pragma unroll
            for (int r = 0; r < 4; ++r) {
                int s = s0 + wave*16 + lq*4 + r;
                oacc[((size_t)(b*S_ + s))*DM_ + h*DK_ + nt*16 + lr] = f2bf(O[nt][r]);
            }
    }
}

// ---------------------------------------------------------------------------
// Output projection: out[m][n] = sum_k AttnOut[m][k]*Wo[n][k] + bo[n] (fp32)
// ---------------------------------------------------------------------------
__global__ __launch_bounds__(256) void outproj_kernel(
        const unsigned short* __restrict__ Xin, const unsigned short* __restrict__ Woh,
        const float* __restrict__ bias, float* __restrict__ out)
{
    __shared__ __align__(16) unsigned short xs[64*72], wsm[64*72];
    const int tid  = threadIdx.x;
    const int wave = tid >> 6, lane = tid & 63, lq = lane >> 4, lr = lane & 15;
    const int m0 = blockIdx.x * 64, n0 = blockIdx.y * 64;

    f32x4 acc[4] = {{0.f,0.f,0.f,0.f},{0.f,0.f,0.f,0.f},
                    {0.f,0.f,0.f,0.f},{0.f,0.f,0.f,0.f}};

    for (int kk = 0; kk < 8; ++kk) {
        __syncthreads();
#pragma unroll
        for (int p = 0; p < 2; ++p) {
            int idx = tid + p*256;
            int row = idx >> 3, seg = idx & 7;
            *(s16x8*)&xs [row*72 + seg*8] =
                *(const s16x8*)&Xin[(size_t)(m0+row)*DM_ + kk*64 + seg*8];
            *(s16x8*)&wsm[row*72 + seg*8] =
                *(const s16x8*)&Woh[(size_t)(n0+row)*DM_ + kk*64 + seg*8];
        }
        __syncthreads();
        const int ar = wave*16 + lr;
        s16x8 a0 = *(const s16x8*)&xs[ar*72 +  0 + lq*8];
        s16x8 a1 = *(const s16x8*)&xs[ar*72 + 32 + lq*8];
#pragma unroll
        for (int nt = 0; nt < 4; ++nt) {
            int br = nt*16 + lr;
            s16x8 b0 = *(const s16x8*)&wsm[br*72 +  0 + lq*8];
            s16x8 b1 = *(const s16x8*)&wsm[br*72 + 32 + lq*8];
            acc[nt] = __builtin_amdgcn_mfma_f32_16x16x32_bf16(a0, b0, acc[nt], 0, 0, 0);
            acc[nt] = __builtin_amdgcn_mfma_f32_16x16x32_bf16(a1, b1, acc[nt], 0, 0, 0);
        }
    }
#pragma unroll
    for (int nt = 0; nt < 4; ++nt)
#pragma unroll
        for (int r = 0; r < 4; ++r) {
            int m = m0 + wave*16 + lq*4 + r;
            int n = n0 + nt*16 + lr;
            out[(size_t)m*DM_ + n] = acc[nt][r] + bias[n];
        }
}

// ---------------------------------------------------------------------------
extern "C" void kernel_launch(void* const* d_in, const int* in_sizes, int n_in,
                              void* d_out, int out_size, void* d_ws, size_t ws_size,
                              hipStream_t stream)
{
    const float* Q  = (const float*)d_in[0];
    const float* K  = (const float*)d_in[1];
    const float* V  = (const float*)d_in[2];
    const float* Wq = (const float*)d_in[3];  const float* bq = (const float*)d_in[4];
    const float* Wk = (const float*)d_in[5];  const float* bk = (const float*)d_in[6];
    const float* Wv = (const float*)d_in[7];  const float* bv = (const float*)d_in[8];
    const float* Wo = (const float*)d_in[9];  const float* bo = (const float*)d_in[10];

    char* ws = (char*)d_ws;
    const size_t QKV_BYTES = (size_t)BH_ * S_ * DK_ * sizeof(unsigned short); // 8,388,608
    const size_t W_BYTES   = (size_t)DM_ * DM_ * sizeof(unsigned short);      //   524,288
    unsigned short* qbf  = (unsigned short*)(ws);
    unsigned short* kbf  = (unsigned short*)(ws + QKV_BYTES);
    unsigned short* vtb  = (unsigned short*)(ws + 2*QKV_BYTES);
    float*          lsum = (float*)(ws + 3*QKV_BYTES);                        // 262,144 B
    unsigned short* oacc = (unsigned short*)(ws + 3*QKV_BYTES + (size_t)BH_*S_*sizeof(float));
    char* p = ws + 4*QKV_BYTES + (size_t)BH_*S_*sizeof(float);
    unsigned short* xh  = (unsigned short*)(p);               p += QKV_BYTES; // 8192x512 bf16
    unsigned short* xl  = (unsigned short*)(p);               p += QKV_BYTES;
    unsigned short* wqh = (unsigned short*)(p);               p += W_BYTES;
    unsigned short* wql = (unsigned short*)(p);               p += W_BYTES;
    unsigned short* wkh = (unsigned short*)(p);               p += W_BYTES;
    unsigned short* wkl = (unsigned short*)(p);               p += W_BYTES;
    unsigned short* wvh = (unsigned short*)(p);               p += W_BYTES;
    unsigned short* wvl = (unsigned short*)(p);               p += W_BYTES;
    unsigned short* woh = (unsigned short*)(p);               p += W_BYTES;   // total ~54.3 MB

    float* out0 = (float*)d_out;
    float* attn = out0 + (size_t)B_ * S_ * DM_;

    dim3 blk(256);
    const int n4x = B_*S_*DM_/4;   // 1,048,576 float4 groups
    const int n4w = DM_*DM_/4;     //    65,536
    auto cgrid = [](int n4) { int g = (n4 + 255) / 256; return g > 2048 ? 2048 : g; };

    convert_split<<<cgrid(n4w), blk, 0, stream>>>(Wq, wqh, wql, n4w);
    convert_split<<<cgrid(n4w), blk, 0, stream>>>(Wk, wkh, wkl, n4w);
    convert_split<<<cgrid(n4w), blk, 0, stream>>>(Wv, wvh, wvl, n4w);
    convert_hi   <<<cgrid(n4w), blk, 0, stream>>>(Wo, woh, n4w);

    convert_split<<<cgrid(n4x), blk, 0, stream>>>(Q, xh, xl, n4x);
    proj_kernel<0><<<dim3(128, 8), blk, 0, stream>>>(xh, xl, wqh, wql, bq, qbf, 0.125f);
    convert_split<<<cgrid(n4x), blk, 0, stream>>>(K, xh, xl, n4x);
    proj_kernel<0><<<dim3(128, 8), blk, 0, stream>>>(xh, xl, wkh, wkl, bk, kbf, 1.0f);
    convert_split<<<cgrid(n4x), blk, 0, stream>>>(V, xh, xl, n4x);
    proj_kernel<1><<<dim3(128, 8), blk, 0, stream>>>(xh, xl, wvh, wvl, bv, vtb, 1.0f);

    stats_kernel  <<<dim3(32, 16), blk, 0, stream>>>(qbf, kbf, lsum);
    attn_kernel   <<<dim3(32, 16), blk, 0, stream>>>(qbf, kbf, vtb, lsum, attn, oacc);
    outproj_kernel<<<dim3(128, 8), blk, 0, stream>>>(oacc, woh, bo, out0);
}

// Round 4
// 1338.199 us; speedup vs baseline: 1.1188x; 1.0145x over previous
//
#include <hip/hip_runtime.h>
#include <stdint.h>

#define B_  2
#define H_  8
#define S_  4096
#define DM_ 512
#define DK_ 64
#define BH_ (B_*H_)

using f32x4 = __attribute__((ext_vector_type(4))) float;
using s16x8 = __attribute__((ext_vector_type(8))) short;
using u16x4 = __attribute__((ext_vector_type(4))) unsigned short;
using u16x8 = __attribute__((ext_vector_type(8))) unsigned short;

__device__ __forceinline__ unsigned short f2bf(float f) {
    unsigned int u = __float_as_uint(f);
    u += 0x7FFFu + ((u >> 16) & 1u);          // RNE
    return (unsigned short)(u >> 16);
}
__device__ __forceinline__ float bf2f(unsigned short h) {
    return __uint_as_float(((unsigned int)h) << 16);
}

// ---------------------------------------------------------------------------
// Pre-pass: fp32 -> bf16 hi + bf16 residual lo (vectorized, grid-stride).
// ---------------------------------------------------------------------------
__global__ __launch_bounds__(256) void convert_split(const float* __restrict__ in,
        unsigned short* __restrict__ hi, unsigned short* __restrict__ lo, int n4)
{
    for (int i = blockIdx.x*256 + threadIdx.x; i < n4; i += gridDim.x*256) {
        float4 v = ((const float4*)in)[i];
        float s4[4] = {v.x, v.y, v.z, v.w};
        u16x4 h, l;
#pragma unroll
        for (int j = 0; j < 4; ++j) {
            unsigned short hh = f2bf(s4[j]);
            h[j] = hh; l[j] = f2bf(s4[j] - bf2f(hh));
        }
        ((u16x4*)hi)[i] = h;
        ((u16x4*)lo)[i] = l;
    }
}

__global__ __launch_bounds__(256) void convert_hi(const float* __restrict__ in,
        unsigned short* __restrict__ hi, int n4)
{
    for (int i = blockIdx.x*256 + threadIdx.x; i < n4; i += gridDim.x*256) {
        float4 v = ((const float4*)in)[i];
        u16x4 h;
        h[0] = f2bf(v.x); h[1] = f2bf(v.y); h[2] = f2bf(v.z); h[3] = f2bf(v.w);
        ((u16x4*)hi)[i] = h;
    }
}

// ---------------------------------------------------------------------------
// Projection GEMM: Y[m][n] = (sum_k X[m][k]*W[n][k] + bias[n]) * scale
// Pure-bf16 inputs (preconverted hi/lo), BK=64, 24 MFMAs per barrier pair.
// MODE 0: Y stored [b][h][s][d]   (q, k)
// MODE 1: Y stored [b][h][d][s]   (v transposed; LDS-restaged epilogue)
// ---------------------------------------------------------------------------
template<int MODE>
__global__ __launch_bounds__(256) void proj_kernel(
        const unsigned short* __restrict__ Xh, const unsigned short* __restrict__ Xl,
        const unsigned short* __restrict__ Wh, const unsigned short* __restrict__ Wl,
        const float* __restrict__ bias, unsigned short* __restrict__ Y, float scale)
{
    __shared__ __align__(16) unsigned short xh[64*72], xl[64*72];
    __shared__ __align__(16) unsigned short wh[64*72], wl[64*72];
    const int tid  = threadIdx.x;
    const int wave = tid >> 6, lane = tid & 63, lq = lane >> 4, lr = lane & 15;
    const int m0 = blockIdx.x * 64, n0 = blockIdx.y * 64;

    f32x4 acc[4] = {{0.f,0.f,0.f,0.f},{0.f,0.f,0.f,0.f},
                    {0.f,0.f,0.f,0.f},{0.f,0.f,0.f,0.f}};

    for (int kk = 0; kk < 8; ++kk) {
        __syncthreads();
#pragma unroll
        for (int p = 0; p < 2; ++p) {
            int idx = tid + p*256;
            int row = idx >> 3, seg = idx & 7;
            size_t xoff = (size_t)(m0+row)*DM_ + kk*64 + seg*8;
            size_t woff = (size_t)(n0+row)*DM_ + kk*64 + seg*8;
            *(u16x8*)&xh[row*72 + seg*8] = *(const u16x8*)&Xh[xoff];
            *(u16x8*)&xl[row*72 + seg*8] = *(const u16x8*)&Xl[xoff];
            *(u16x8*)&wh[row*72 + seg*8] = *(const u16x8*)&Wh[woff];
            *(u16x8*)&wl[row*72 + seg*8] = *(const u16x8*)&Wl[woff];
        }
        __syncthreads();
        const int ar = wave*16 + lr;
        s16x8 ah0 = *(const s16x8*)&xh[ar*72 +  0 + lq*8];
        s16x8 ah1 = *(const s16x8*)&xh[ar*72 + 32 + lq*8];
        s16x8 al0 = *(const s16x8*)&xl[ar*72 +  0 + lq*8];
        s16x8 al1 = *(const s16x8*)&xl[ar*72 + 32 + lq*8];
#pragma unroll
        for (int nt = 0; nt < 4; ++nt) {
            int br = nt*16 + lr;
            s16x8 bh0 = *(const s16x8*)&wh[br*72 +  0 + lq*8];
            s16x8 bh1 = *(const s16x8*)&wh[br*72 + 32 + lq*8];
            s16x8 bl0 = *(const s16x8*)&wl[br*72 +  0 + lq*8];
            s16x8 bl1 = *(const s16x8*)&wl[br*72 + 32 + lq*8];
            acc[nt] = __builtin_amdgcn_mfma_f32_16x16x32_bf16(ah0, bh0, acc[nt], 0, 0, 0);
            acc[nt] = __builtin_amdgcn_mfma_f32_16x16x32_bf16(ah0, bl0, acc[nt], 0, 0, 0);
            acc[nt] = __builtin_amdgcn_mfma_f32_16x16x32_bf16(al0, bh0, acc[nt], 0, 0, 0);
            acc[nt] = __builtin_amdgcn_mfma_f32_16x16x32_bf16(ah1, bh1, acc[nt], 0, 0, 0);
            acc[nt] = __builtin_amdgcn_mfma_f32_16x16x32_bf16(ah1, bl1, acc[nt], 0, 0, 0);
            acc[nt] = __builtin_amdgcn_mfma_f32_16x16x32_bf16(al1, bh1, acc[nt], 0, 0, 0);
        }
    }
    if (MODE == 0) {
#pragma unroll
        for (int nt = 0; nt < 4; ++nt)
#pragma unroll
            for (int r = 0; r < 4; ++r) {
                int m = m0 + wave*16 + lq*4 + r;
                int n = n0 + nt*16 + lr;
                float v = (acc[nt][r] + bias[n]) * scale;
                int b = m >> 12, s = m & 4095;
                int h = n >> 6,  d = n & 63;
                Y[((size_t)((b*H_ + h)*S_ + s))*DK_ + d] = f2bf(v);
            }
    } else {
        // Restage 64x64 tile through LDS (reuse xh), store rows along s.
        __syncthreads();
#pragma unroll
        for (int nt = 0; nt < 4; ++nt)
#pragma unroll
            for (int r = 0; r < 4; ++r) {
                int ml = wave*16 + lq*4 + r;    // s_local
                int nl = nt*16 + lr;            // d
                float v = (acc[nt][r] + bias[n0 + nl]) * scale;
                xh[nl*72 + ml] = f2bf(v);
            }
        __syncthreads();
        const int b = m0 >> 12, sbase = m0 & 4095, h = n0 >> 6;
        const int row = tid >> 2, segb = (tid & 3) * 16;
        size_t base = ((size_t)((b*H_ + h)*DK_ + row))*S_ + sbase + segb;
        *(u16x8*)&Y[base]     = *(const u16x8*)&xh[row*72 + segb];
        *(u16x8*)&Y[base + 8] = *(const u16x8*)&xh[row*72 + segb + 8];
    }
}

// ---------------------------------------------------------------------------
// Stats pass: l[bh][sq] = sum_{j<=sq} exp(s(sq,j) - 16).
// Paired row-blocks (uniform 65 tiles/block) + double-buffered K staging with
// issue-early / ds_write-late (T14): 1 barrier/tile, load latency hidden.
// ---------------------------------------------------------------------------
__global__ __launch_bounds__(256) void stats_kernel(
        const unsigned short* __restrict__ qb, const unsigned short* __restrict__ kb,
        float* __restrict__ lsum)
{
    __shared__ __align__(16) unsigned short qs[64*72];
    __shared__ __align__(16) unsigned short ks[2][64*72];
    const int tid  = threadIdx.x;
    const int wave = tid >> 6, lane = tid & 63, lq = lane >> 4, lr = lane & 15;
    const int bh = blockIdx.y;
    const int row8 = tid >> 3, seg8 = tid & 7;   // staging coords (idx<256)
    const int row8b = row8 + 32;                 // second phase rows

#pragma unroll 1
    for (int half = 0; half < 2; ++half) {
        const int bx = half ? (63 - blockIdx.x) : blockIdx.x;
        const int s0 = bx * 64;
        __syncthreads();   // protect qs/ks reuse across halves
        // stage Q
#pragma unroll
        for (int p = 0; p < 2; ++p) {
            int idx = tid + p*256;
            int row = idx >> 3, seg = idx & 7;
            *(s16x8*)&qs[row*72 + seg*8] =
                *(const s16x8*)&qb[((size_t)bh*S_ + s0 + row)*DK_ + seg*8];
        }
        // prologue: stage K tile 0 into ks[0]
        {
            u16x8 k0 = *(const u16x8*)&kb[((size_t)bh*S_ + row8 )*DK_ + seg8*8];
            u16x8 k1 = *(const u16x8*)&kb[((size_t)bh*S_ + row8b)*DK_ + seg8*8];
            *(u16x8*)&ks[0][row8 *72 + seg8*8] = k0;
            *(u16x8*)&ks[0][row8b*72 + seg8*8] = k1;
        }
        __syncthreads();
        const int ar = wave*16 + lr;
        s16x8 aq0 = *(const s16x8*)&qs[ar*72 +  0 + lq*8];
        s16x8 aq1 = *(const s16x8*)&qs[ar*72 + 32 + lq*8];

        float lacc[4] = {0.f, 0.f, 0.f, 0.f};
        int cur = 0;
        for (int jt = 0; jt <= bx; ++jt) {
            u16x8 k0, k1;
            if (jt < bx) {   // issue next-tile loads early (latency hides under MFMA/exp)
                k0 = *(const u16x8*)&kb[((size_t)bh*S_ + (jt+1)*64 + row8 )*DK_ + seg8*8];
                k1 = *(const u16x8*)&kb[((size_t)bh*S_ + (jt+1)*64 + row8b)*DK_ + seg8*8];
            }
#pragma unroll
            for (int nt = 0; nt < 4; ++nt) {
                int br = nt*16 + lr;
                s16x8 b0 = *(const s16x8*)&ks[cur][br*72 +  0 + lq*8];
                s16x8 b1 = *(const s16x8*)&ks[cur][br*72 + 32 + lq*8];
                f32x4 sc = {0.f,0.f,0.f,0.f};
                sc = __builtin_amdgcn_mfma_f32_16x16x32_bf16(aq0, b0, sc, 0, 0, 0);
                sc = __builtin_amdgcn_mfma_f32_16x16x32_bf16(aq1, b1, sc, 0, 0, 0);
                int j = jt*64 + nt*16 + lr;
#pragma unroll
                for (int r = 0; r < 4; ++r) {
                    int sq = s0 + wave*16 + lq*4 + r;
                    lacc[r] += (j <= sq) ? __expf(sc[r] - 16.f) : 0.f;
                }
            }
            if (jt < bx) {   // write-late into the other buffer
                *(u16x8*)&ks[cur^1][row8 *72 + seg8*8] = k0;
                *(u16x8*)&ks[cur^1][row8b*72 + seg8*8] = k1;
            }
            __syncthreads();
            cur ^= 1;
        }
#pragma unroll
        for (int r = 0; r < 4; ++r) {
            float v = lacc[r];
            for (int off = 1; off < 16; off <<= 1) v += __shfl_xor(v, off, 64);
            if (lr == 0) lsum[(size_t)bh*S_ + s0 + wave*16 + lq*4 + r] = v;
        }
    }
}

// ---------------------------------------------------------------------------
// Pass 2: recompute scores, attn = exp(s-16)/l, write attn (fp32, nontemporal),
// wave-local LDS round-trip attn->A-frag, PV MFMA, store O bf16 [b][s][hd].
// Paired row-blocks + double-buffered K/V staging (issue-early/write-late):
// 1 barrier/tile (was 2), staging latency hidden under QK+exp+PV.
// Zero-fill of the masked upper triangle moved to a barrier-free tail loop.
// ---------------------------------------------------------------------------
__global__ __launch_bounds__(256) void attn_kernel(
        const unsigned short* __restrict__ qb, const unsigned short* __restrict__ kb,
        const unsigned short* __restrict__ vtb, const float* __restrict__ lsum,
        float* __restrict__ attn, unsigned short* __restrict__ oacc)
{
    __shared__ __align__(16) unsigned short qs[64*72];
    __shared__ __align__(16) unsigned short ks[2][64*72], vs[2][64*72];
    __shared__ __align__(16) unsigned short ps[4][16*72];
    __shared__ float invl[64];
    const int tid  = threadIdx.x;
    const int wave = tid >> 6, lane = tid & 63, lq = lane >> 4, lr = lane & 15;
    const int bh = blockIdx.y;
    const int row8 = tid >> 3, seg8 = tid & 7;
    const int row8b = row8 + 32;

#pragma unroll 1
    for (int half = 0; half < 2; ++half) {
        const int bx = half ? (63 - blockIdx.x) : blockIdx.x;
        const int s0 = bx * 64;
        __syncthreads();   // protect qs/ks/vs/invl reuse across halves
#pragma unroll
        for (int p = 0; p < 2; ++p) {
            int idx = tid + p*256;
            int row = idx >> 3, seg = idx & 7;
            *(s16x8*)&qs[row*72 + seg*8] =
                *(const s16x8*)&qb[((size_t)bh*S_ + s0 + row)*DK_ + seg*8];
        }
        if (tid < 64) invl[tid] = 1.0f / lsum[(size_t)bh*S_ + s0 + tid];
        // prologue: stage K/V tile 0
        {
            u16x8 k0 = *(const u16x8*)&kb [((size_t)bh*S_  + row8 )*DK_ + seg8*8];
            u16x8 k1 = *(const u16x8*)&kb [((size_t)bh*S_  + row8b)*DK_ + seg8*8];
            u16x8 v0 = *(const u16x8*)&vtb[((size_t)bh*DK_ + row8 )*S_  + seg8*8];
            u16x8 v1 = *(const u16x8*)&vtb[((size_t)bh*DK_ + row8b)*S_  + seg8*8];
            *(u16x8*)&ks[0][row8 *72 + seg8*8] = k0;
            *(u16x8*)&ks[0][row8b*72 + seg8*8] = k1;
            *(u16x8*)&vs[0][row8 *72 + seg8*8] = v0;
            *(u16x8*)&vs[0][row8b*72 + seg8*8] = v1;
        }
        __syncthreads();
        const int ar = wave*16 + lr;
        s16x8 aq0 = *(const s16x8*)&qs[ar*72 +  0 + lq*8];
        s16x8 aq1 = *(const s16x8*)&qs[ar*72 + 32 + lq*8];
        float il[4];
#pragma unroll
        for (int r = 0; r < 4; ++r) il[r] = invl[wave*16 + lq*4 + r];

        f32x4 O[4] = {{0.f,0.f,0.f,0.f},{0.f,0.f,0.f,0.f},
                      {0.f,0.f,0.f,0.f},{0.f,0.f,0.f,0.f}};
        int cur = 0;
        for (int jt = 0; jt <= bx; ++jt) {
            u16x8 k0, k1, v0, v1;
            if (jt < bx) {   // issue next-tile loads early
                k0 = *(const u16x8*)&kb [((size_t)bh*S_  + (jt+1)*64 + row8 )*DK_ + seg8*8];
                k1 = *(const u16x8*)&kb [((size_t)bh*S_  + (jt+1)*64 + row8b)*DK_ + seg8*8];
                v0 = *(const u16x8*)&vtb[((size_t)bh*DK_ + row8 )*S_ + (jt+1)*64 + seg8*8];
                v1 = *(const u16x8*)&vtb[((size_t)bh*DK_ + row8b)*S_ + (jt+1)*64 + seg8*8];
            }
            float a_all[4][4];
#pragma unroll
            for (int nt = 0; nt < 4; ++nt) {
                int br = nt*16 + lr;
                s16x8 b0 = *(const s16x8*)&ks[cur][br*72 +  0 + lq*8];
                s16x8 b1 = *(const s16x8*)&ks[cur][br*72 + 32 + lq*8];
                f32x4 sc = {0.f,0.f,0.f,0.f};
                sc = __builtin_amdgcn_mfma_f32_16x16x32_bf16(aq0, b0, sc, 0, 0, 0);
                sc = __builtin_amdgcn_mfma_f32_16x16x32_bf16(aq1, b1, sc, 0, 0, 0);
                int j = jt*64 + nt*16 + lr;
#pragma unroll
                for (int r = 0; r < 4; ++r) {
                    int sq = s0 + wave*16 + lq*4 + r;
                    float p = (j <= sq) ? __expf(sc[r] - 16.f) : 0.f;
                    float a = p * il[r];
                    a_all[nt][r] = a;
                    ps[wave][(lq*4 + r)*72 + nt*16 + lr] = f2bf(a);
                }
            }
            // ps written and read by the SAME wave: wave-local drain only.
            asm volatile("s_waitcnt lgkmcnt(0)" ::: "memory");
            __builtin_amdgcn_sched_barrier(0);
            s16x8 ap0 = *(const s16x8*)&ps[wave][lr*72 +  0 + lq*8];
            s16x8 ap1 = *(const s16x8*)&ps[wave][lr*72 + 32 + lq*8];
#pragma unroll
            for (int nt = 0; nt < 4; ++nt) {
                s16x8 bv0 = *(const s16x8*)&vs[cur][(nt*16 + lr)*72 +  0 + lq*8];
                s16x8 bv1 = *(const s16x8*)&vs[cur][(nt*16 + lr)*72 + 32 + lq*8];
                O[nt] = __builtin_amdgcn_mfma_f32_16x16x32_bf16(ap0, bv0, O[nt], 0, 0, 0);
                O[nt] = __builtin_amdgcn_mfma_f32_16x16x32_bf16(ap1, bv1, O[nt], 0, 0, 0);
            }
            // attn stores after PV so their drain overlaps the MFMAs.
#pragma unroll
            for (int nt = 0; nt < 4; ++nt)
#pragma unroll
                for (int r = 0; r < 4; ++r) {
                    int sq = s0 + wave*16 + lq*4 + r;
                    __builtin_nontemporal_store(a_all[nt][r],
                        &attn[((size_t)bh*S_ + sq)*S_ + jt*64 + nt*16 + lr]);
                }
            if (jt < bx) {   // write-late into the other buffer
                *(u16x8*)&ks[cur^1][row8 *72 + seg8*8] = k0;
                *(u16x8*)&ks[cur^1][row8b*72 + seg8*8] = k1;
                *(u16x8*)&vs[cur^1][row8 *72 + seg8*8] = v0;
                *(u16x8*)&vs[cur^1][row8b*72 + seg8*8] = v1;
            }
            __syncthreads();
            cur ^= 1;
        }
        // fully-masked tiles: barrier-free zero fill (upper triangle = 0.0f)
        for (int jt = bx + 1; jt < S_/64; ++jt) {
#pragma unroll
            for (int p = 0; p < 4; ++p) {
                int idx = tid + p*256;
                int row = idx >> 4, c4 = idx & 15;
                f32x4 z = {0.f, 0.f, 0.f, 0.f};
                __builtin_nontemporal_store(z,
                    (f32x4*)&attn[((size_t)bh*S_ + s0 + row)*S_ + jt*64 + c4*4]);
            }
        }
        const int b = bh >> 3, h = bh & 7;
#pragma unroll
        for (int nt = 0; nt < 4; ++nt)
#pragma unroll
            for (int r = 0; r < 4; ++r) {
                int s = s0 + wave*16 + lq*4 + r;
                oacc[((size_t)(b*S_ + s))*DM_ + h*DK_ + nt*16 + lr] = f2bf(O[nt][r]);
            }
    }
}

// ---------------------------------------------------------------------------
// Output projection: out[m][n] = sum_k AttnOut[m][k]*Wo[n][k] + bo[n] (fp32)
// ---------------------------------------------------------------------------
__global__ __launch_bounds__(256) void outproj_kernel(
        const unsigned short* __restrict__ Xin, const unsigned short* __restrict__ Woh,
        const float* __restrict__ bias, float* __restrict__ out)
{
    __shared__ __align__(16) unsigned short xs[64*72], wsm[64*72];
    const int tid  = threadIdx.x;
    const int wave = tid >> 6, lane = tid & 63, lq = lane >> 4, lr = lane & 15;
    const int m0 = blockIdx.x * 64, n0 = blockIdx.y * 64;

    f32x4 acc[4] = {{0.f,0.f,0.f,0.f},{0.f,0.f,0.f,0.f},
                    {0.f,0.f,0.f,0.f},{0.f,0.f,0.f,0.f}};

    for (int kk = 0; kk < 8; ++kk) {
        __syncthreads();
#pragma unroll
        for (int p = 0; p < 2; ++p) {
            int idx = tid + p*256;
            int row = idx >> 3, seg = idx & 7;
            *(s16x8*)&xs [row*72 + seg*8] =
                *(const s16x8*)&Xin[(size_t)(m0+row)*DM_ + kk*64 + seg*8];
            *(s16x8*)&wsm[row*72 + seg*8] =
                *(const s16x8*)&Woh[(size_t)(n0+row)*DM_ + kk*64 + seg*8];
        }
        __syncthreads();
        const int ar = wave*16 + lr;
        s16x8 a0 = *(const s16x8*)&xs[ar*72 +  0 + lq*8];
        s16x8 a1 = *(const s16x8*)&xs[ar*72 + 32 + lq*8];
#pragma unroll
        for (int nt = 0; nt < 4; ++nt) {
            int br = nt*16 + lr;
            s16x8 b0 = *(const s16x8*)&wsm[br*72 +  0 + lq*8];
            s16x8 b1 = *(const s16x8*)&wsm[br*72 + 32 + lq*8];
            acc[nt] = __builtin_amdgcn_mfma_f32_16x16x32_bf16(a0, b0, acc[nt], 0, 0, 0);
            acc[nt] = __builtin_amdgcn_mfma_f32_16x16x32_bf16(a1, b1, acc[nt], 0, 0, 0);
        }
    }
#pragma unroll
    for (int nt = 0; nt < 4; ++nt)
#pragma unroll
        for (int r = 0; r < 4; ++r) {
            int m = m0 + wave*16 + lq*4 + r;
            int n = n0 + nt*16 + lr;
            out[(size_t)m*DM_ + n] = acc[nt][r] + bias[n];
        }
}

// ---------------------------------------------------------------------------
extern "C" void kernel_launch(void* const* d_in, const int* in_sizes, int n_in,
                              void* d_out, int out_size, void* d_ws, size_t ws_size,
                              hipStream_t stream)
{
    const float* Q  = (const float*)d_in[0];
    const float* K  = (const float*)d_in[1];
    const float* V  = (const float*)d_in[2];
    const float* Wq = (const float*)d_in[3];  const float* bq = (const float*)d_in[4];
    const float* Wk = (const float*)d_in[5];  const float* bk = (const float*)d_in[6];
    const float* Wv = (const float*)d_in[7];  const float* bv = (const float*)d_in[8];
    const float* Wo = (const float*)d_in[9];  const float* bo = (const float*)d_in[10];

    char* ws = (char*)d_ws;
    const size_t QKV_BYTES = (size_t)BH_ * S_ * DK_ * sizeof(unsigned short); // 8,388,608
    const size_t W_BYTES   = (size_t)DM_ * DM_ * sizeof(unsigned short);      //   524,288
    unsigned short* qbf  = (unsigned short*)(ws);
    unsigned short* kbf  = (unsigned short*)(ws + QKV_BYTES);
    unsigned short* vtb  = (unsigned short*)(ws + 2*QKV_BYTES);
    float*          lsum = (float*)(ws + 3*QKV_BYTES);                        // 262,144 B
    unsigned short* oacc = (unsigned short*)(ws + 3*QKV_BYTES + (size_t)BH_*S_*sizeof(float));
    char* p = ws + 4*QKV_BYTES + (size_t)BH_*S_*sizeof(float);
    unsigned short* xh  = (unsigned short*)(p);               p += QKV_BYTES; // 8192x512 bf16
    unsigned short* xl  = (unsigned short*)(p);               p += QKV_BYTES;
    unsigned short* wqh = (unsigned short*)(p);               p += W_BYTES;
    unsigned short* wql = (unsigned short*)(p);               p += W_BYTES;
    unsigned short* wkh = (unsigned short*)(p);               p += W_BYTES;
    unsigned short* wkl = (unsigned short*)(p);               p += W_BYTES;
    unsigned short* wvh = (unsigned short*)(p);               p += W_BYTES;
    unsigned short* wvl = (unsigned short*)(p);               p += W_BYTES;
    unsigned short* woh = (unsigned short*)(p);               p += W_BYTES;   // total ~54.3 MB

    float* out0 = (float*)d_out;
    float* attn = out0 + (size_t)B_ * S_ * DM_;

    dim3 blk(256);
    const int n4x = B_*S_*DM_/4;   // 1,048,576 float4 groups
    const int n4w = DM_*DM_/4;     //    65,536
    auto cgrid = [](int n4) { int g = (n4 + 255) / 256; return g > 2048 ? 2048 : g; };

    convert_split<<<cgrid(n4w), blk, 0, stream>>>(Wq, wqh, wql, n4w);
    convert_split<<<cgrid(n4w), blk, 0, stream>>>(Wk, wkh, wkl, n4w);
    convert_split<<<cgrid(n4w), blk, 0, stream>>>(Wv, wvh, wvl, n4w);
    convert_hi   <<<cgrid(n4w), blk, 0, stream>>>(Wo, woh, n4w);

    convert_split<<<cgrid(n4x), blk, 0, stream>>>(Q, xh, xl, n4x);
    proj_kernel<0><<<dim3(128, 8), blk, 0, stream>>>(xh, xl, wqh, wql, bq, qbf, 0.125f);
    convert_split<<<cgrid(n4x), blk, 0, stream>>>(K, xh, xl, n4x);
    proj_kernel<0><<<dim3(128, 8), blk, 0, stream>>>(xh, xl, wkh, wkl, bk, kbf, 1.0f);
    convert_split<<<cgrid(n4x), blk, 0, stream>>>(V, xh, xl, n4x);
    proj_kernel<1><<<dim3(128, 8), blk, 0, stream>>>(xh, xl, wvh, wvl, bv, vtb, 1.0f);

    stats_kernel  <<<dim3(32, 16), blk, 0, stream>>>(qbf, kbf, lsum);
    attn_kernel   <<<dim3(32, 16), blk, 0, stream>>>(qbf, kbf, vtb, lsum, attn, oacc);
    outproj_kernel<<<dim3(128, 8), blk, 0, stream>>>(oacc, woh, bo, out0);
}